// Round 3
// baseline (2419.092 us; speedup 1.0000x reference)
//
#include <hip/hip_runtime.h>
#include <hip/hip_bf16.h>
#include <stdint.h>

// Problem: B=1, S_IMG=1536, S_TXT=512, D=3072, H=24, HD=128, R=32.
// Harness dtypes: ALL inputs float32, output float32. Internal MFMA in bf16.
typedef __hip_bfloat16 bf16;
typedef __attribute__((ext_vector_type(8))) short short8;   // 8 bf16 (16B)
typedef __attribute__((ext_vector_type(4))) short short4b;  // 4 bf16 (8B)
typedef __attribute__((ext_vector_type(4))) float floatx4;  // MFMA C/D

__device__ __forceinline__ short bfs(float x) {
    // RNE f32 -> bf16, returned as raw bits
    uint32_t u = __builtin_bit_cast(uint32_t, x);
    u += 0x7FFFu + ((u >> 16) & 1u);
    return (short)(u >> 16);
}
__device__ __forceinline__ float b2f(bf16 x) { return __bfloat162float(x); }

// ---------------------------------------------------------------------------
// upT[n][r] = up[r][n]   (up is [32][N] row-major, f32 -> f32)
__global__ __launch_bounds__(64) void transposeR(const float* __restrict__ U,
                                                 float* __restrict__ UT, int N) {
    const int n = blockIdx.x * 64 + threadIdx.x;
    #pragma unroll
    for (int r = 0; r < 32; ++r)
        UT[(size_t)n * 32 + r] = U[(size_t)r * N + n];
}

// ---------------------------------------------------------------------------
// t[m][r] = sum_k x[m][k] * down[k][r]   (K=3072, R=32). One block per row m.
__global__ __launch_bounds__(256) void downproj(const float* __restrict__ X,
                                                const float* __restrict__ Dn,
                                                float* __restrict__ T, int K) {
    const int m = blockIdx.x;
    const int n = threadIdx.x & 31;
    const int kg = threadIdx.x >> 5;           // 8 K-groups
    const float* x = X + (size_t)m * K;
    const int kc = K >> 3;                     // 384
    float acc = 0.f;
    #pragma unroll 4
    for (int k = kg * kc; k < (kg + 1) * kc; ++k)
        acc += x[k] * Dn[(size_t)k * 32 + n];
    __shared__ float red[8][32];
    red[kg][n] = acc;
    __syncthreads();
    if (threadIdx.x < 32) {
        float s = 0.f;
        #pragma unroll
        for (int g = 0; g < 8; ++g) s += red[g][n];
        T[(size_t)m * 32 + n] = s;
    }
}

// ---------------------------------------------------------------------------
// C = A @ B^T + t @ upT^T (+bias). A:[M][K], B:[N][K], t:[M][32], upT:[N][32],
// all f32 in global; converted to bf16 during LDS staging. Low-rank term is
// one extra K-step. mode 0: write C row-major [M][N] f32. mode 1: scatter to
//   Q[h][s][128], K[h][s][128], V[h][128][s] (bf16), s = s_base + row.
__global__ __launch_bounds__(256) void gemm128(
    const float* __restrict__ A, const float* __restrict__ B,
    const float* __restrict__ T, const float* __restrict__ UpT,
    const float* __restrict__ bias, float* __restrict__ C,
    bf16* __restrict__ Qb, bf16* __restrict__ Kb, bf16* __restrict__ Vb,
    int M, int N, int K, int s_base, int mode)
{
    __shared__ __align__(16) bf16 As[128 * 32];
    __shared__ __align__(16) bf16 Bs[128 * 32];
    const int tid = threadIdx.x;
    const int lane = tid & 63, w = tid >> 6;
    const int wm = (w >> 1) * 64, wn = (w & 1) * 64;
    const int lr = lane & 15, lq = lane >> 4;
    const int m0 = blockIdx.y * 128, n0 = blockIdx.x * 128;

    floatx4 acc[4][4] = {};
    const int ksteps = K >> 5;
    for (int kt = 0; kt <= ksteps; ++kt) {
        const float *a_src, *b_src;
        int lda, ldb;
        if (kt < ksteps) {
            a_src = A + (size_t)m0 * K + kt * 32; lda = K;
            b_src = B + (size_t)n0 * K + kt * 32; ldb = K;
        } else {                                  // low-rank K-step
            a_src = T   + (size_t)m0 * 32; lda = 32;
            b_src = UpT + (size_t)n0 * 32; ldb = 32;
        }
        __syncthreads();
        // stage+convert: 128 rows x 32 f32 -> bf16 ; 1024 chunks of 4 floats
        #pragma unroll
        for (int c = tid; c < 1024; c += 256) {
            const int row = c >> 3, cg = c & 7;
            const float4 v = *(const float4*)(a_src + (size_t)row * lda + cg * 4);
            short4b o = { bfs(v.x), bfs(v.y), bfs(v.z), bfs(v.w) };
            *(short4b*)(As + row * 32 + cg * 4) = o;
        }
        #pragma unroll
        for (int c = tid; c < 1024; c += 256) {
            const int row = c >> 3, cg = c & 7;
            const float4 v = *(const float4*)(b_src + (size_t)row * ldb + cg * 4);
            short4b o = { bfs(v.x), bfs(v.y), bfs(v.z), bfs(v.w) };
            *(short4b*)(Bs + row * 32 + cg * 4) = o;
        }
        __syncthreads();
        short8 af[4], bfr[4];
        #pragma unroll
        for (int i = 0; i < 4; ++i)
            af[i] = *(const short8*)(As + (wm + i * 16 + lr) * 32 + lq * 8);
        #pragma unroll
        for (int j = 0; j < 4; ++j)
            bfr[j] = *(const short8*)(Bs + (wn + j * 16 + lr) * 32 + lq * 8);
        #pragma unroll
        for (int i = 0; i < 4; ++i)
            #pragma unroll
            for (int j = 0; j < 4; ++j)
                acc[i][j] = __builtin_amdgcn_mfma_f32_16x16x32_bf16(
                    af[i], bfr[j], acc[i][j], 0, 0, 0);
    }

    if (mode == 0) {
        #pragma unroll
        for (int j = 0; j < 4; ++j) {
            const int col = n0 + wn + j * 16 + lr;
            const float bv = bias ? bias[col] : 0.0f;
            #pragma unroll
            for (int i = 0; i < 4; ++i) {
                const int rowb = m0 + wm + i * 16 + lq * 4;
                #pragma unroll
                for (int r = 0; r < 4; ++r)
                    C[(size_t)(rowb + r) * N + col] = acc[i][j][r] + bv;
            }
        }
    } else {
        #pragma unroll
        for (int j = 0; j < 4; ++j) {
            const int col = n0 + wn + j * 16 + lr;
            const int which = col / 3072;
            const int cc = col - which * 3072;
            const int hh = cc >> 7, dd = cc & 127;
            #pragma unroll
            for (int i = 0; i < 4; ++i) {
                const int rowb = m0 + wm + i * 16 + lq * 4;
                #pragma unroll
                for (int r = 0; r < 4; ++r) {
                    const int s = s_base + rowb + r;
                    const bf16 v = __float2bfloat16(acc[i][j][r]);
                    if (which == 0)
                        Qb[((size_t)hh * 2048 + s) * 128 + dd] = v;
                    else if (which == 1)
                        Kb[((size_t)hh * 2048 + s) * 128 + dd] = v;
                    else
                        Vb[((size_t)hh * 128 + dd) * 2048 + s] = v;  // V^T
                }
            }
        }
    }
}

// ---------------------------------------------------------------------------
// RMSNorm (per (s,h) row of 128) + RoPE, in-place on Q and K (bf16 buffers).
// cos/sin/norm-weights are f32 inputs. 1 wave/block.
__global__ __launch_bounds__(64) void rmsrope(
    bf16* __restrict__ Qb, bf16* __restrict__ Kb,
    const float* __restrict__ cosb, const float* __restrict__ sinb,
    const float* __restrict__ nqw, const float* __restrict__ nkw,
    const float* __restrict__ naqw, const float* __restrict__ nakw)
{
    const int s = blockIdx.x & 2047;
    const int h = blockIdx.x >> 11;
    const int i = threadIdx.x;                       // pair index 0..63
    const float c  = cosb[s * 64 + i];
    const float sn = sinb[s * 64 + i];
    const bool txt = (s < 512);
    const size_t base = ((size_t)h * 2048 + s) * 128;

    {
        __hip_bfloat162* row = (__hip_bfloat162*)(Qb + base);
        __hip_bfloat162 pv = row[i];
        float x0 = b2f(pv.x), x1 = b2f(pv.y);
        float ss = x0 * x0 + x1 * x1;
        #pragma unroll
        for (int m = 1; m < 64; m <<= 1) ss += __shfl_xor(ss, m);
        const float rms = rsqrtf(ss * (1.0f / 128.0f) + 1e-5f);
        const float* nw = txt ? naqw : nqw;
        const float y0 = x0 * rms * nw[2 * i];
        const float y1 = x1 * rms * nw[2 * i + 1];
        __hip_bfloat162 o;
        o.x = __float2bfloat16(y0 * c - y1 * sn);
        o.y = __float2bfloat16(y0 * sn + y1 * c);
        row[i] = o;
    }
    {
        __hip_bfloat162* row = (__hip_bfloat162*)(Kb + base);
        __hip_bfloat162 pv = row[i];
        float x0 = b2f(pv.x), x1 = b2f(pv.y);
        float ss = x0 * x0 + x1 * x1;
        #pragma unroll
        for (int m = 1; m < 64; m <<= 1) ss += __shfl_xor(ss, m);
        const float rms = rsqrtf(ss * (1.0f / 128.0f) + 1e-5f);
        const float* nw = txt ? nakw : nkw;
        const float y0 = x0 * rms * nw[2 * i];
        const float y1 = x1 * rms * nw[2 * i + 1];
        __hip_bfloat162 o;
        o.x = __float2bfloat16(y0 * c - y1 * sn);
        o.y = __float2bfloat16(y0 * sn + y1 * c);
        row[i] = o;
    }
}

// ---------------------------------------------------------------------------
// Flash attention: block = 64 q-rows of one head; KV tiles of 64; 4 waves,
// each wave owns 16 q-rows x full HD=128. Online softmax in registers.
// Output attnb is f32 [s][3072].
__global__ __launch_bounds__(256) void attn64(
    const bf16* __restrict__ Qb, const bf16* __restrict__ Kb,
    const bf16* __restrict__ Vb, float* __restrict__ attnb)
{
    __shared__ __align__(16) bf16 Ks[64 * 128];     // [kv][d]
    __shared__ __align__(16) bf16 VsT[128 * 64];    // [d][kv]
    __shared__ __align__(16) bf16 Ps[4][16][72];    // per-wave P, 72 keeps 16B align
    const int tid = threadIdx.x, lane = tid & 63, w = tid >> 6;
    const int lr = lane & 15, lq = lane >> 4;
    const int h = blockIdx.y, q0 = blockIdx.x * 64;
    const float scale = 0.08838834764831845f;   // 1/sqrt(128)

    // Q fragments for this wave's 16 rows (kept in registers whole kernel)
    const bf16* qrow = Qb + ((size_t)h * 2048 + q0 + w * 16 + lr) * 128;
    short8 qf[4];
    #pragma unroll
    for (int ks = 0; ks < 4; ++ks)
        qf[ks] = *(const short8*)(qrow + ks * 32 + lq * 8);

    floatx4 oacc[8] = {};
    float mrow[4] = {-1e30f, -1e30f, -1e30f, -1e30f};
    float lrow[4] = {0.f, 0.f, 0.f, 0.f};

    for (int kt = 0; kt < 32; ++kt) {
        const int kv0 = kt * 64;
        __syncthreads();
        // Ks: 64 rows x 128 cols = 1024 chunks of 16B
        #pragma unroll
        for (int c = tid; c < 1024; c += 256) {
            const int row = c >> 4, cg = c & 15;
            *(short8*)(Ks + c * 8) =
                *(const short8*)(Kb + ((size_t)h * 2048 + kv0 + row) * 128 + cg * 8);
        }
        // VsT: 128 rows x 64 cols = 1024 chunks of 16B
        #pragma unroll
        for (int c = tid; c < 1024; c += 256) {
            const int row = c >> 3, cg = c & 7;
            *(short8*)(VsT + c * 8) =
                *(const short8*)(Vb + ((size_t)h * 128 + row) * 2048 + kv0 + cg * 8);
        }
        __syncthreads();

        // S = Q K^T for 16 q x 64 kv
        floatx4 sacc[4] = {};
        #pragma unroll
        for (int ks = 0; ks < 4; ++ks)
            #pragma unroll
            for (int jt = 0; jt < 4; ++jt) {
                short8 kf = *(const short8*)(Ks + (jt * 16 + lr) * 128 + ks * 32 + lq * 8);
                sacc[jt] = __builtin_amdgcn_mfma_f32_16x16x32_bf16(qf[ks], kf, sacc[jt], 0, 0, 0);
            }

        // online softmax (lane holds rows lq*4+r, col lr of each 16-block)
        float alpha_r[4];
        #pragma unroll
        for (int r = 0; r < 4; ++r) {
            float s0 = sacc[0][r] * scale, s1 = sacc[1][r] * scale;
            float s2 = sacc[2][r] * scale, s3 = sacc[3][r] * scale;
            float mx = fmaxf(fmaxf(s0, s1), fmaxf(s2, s3));
            #pragma unroll
            for (int msk = 1; msk < 16; msk <<= 1)
                mx = fmaxf(mx, __shfl_xor(mx, msk));
            const float mn = fmaxf(mrow[r], mx);
            const float al = __expf(mrow[r] - mn);
            s0 = __expf(s0 - mn); s1 = __expf(s1 - mn);
            s2 = __expf(s2 - mn); s3 = __expf(s3 - mn);
            float sum = s0 + s1 + s2 + s3;
            #pragma unroll
            for (int msk = 1; msk < 16; msk <<= 1)
                sum += __shfl_xor(sum, msk);
            lrow[r] = lrow[r] * al + sum;
            mrow[r] = mn;
            alpha_r[r] = al;
            sacc[0][r] = s0; sacc[1][r] = s1; sacc[2][r] = s2; sacc[3][r] = s3;
        }
        #pragma unroll
        for (int nt = 0; nt < 8; ++nt)
            #pragma unroll
            for (int r = 0; r < 4; ++r) oacc[nt][r] *= alpha_r[r];

        // P: C-layout -> LDS -> A-layout
        #pragma unroll
        for (int jt = 0; jt < 4; ++jt)
            #pragma unroll
            for (int r = 0; r < 4; ++r)
                Ps[w][lq * 4 + r][jt * 16 + lr] = __float2bfloat16(sacc[jt][r]);
        __syncthreads();

        short8 pf[2];
        #pragma unroll
        for (int k2 = 0; k2 < 2; ++k2)
            pf[k2] = *(const short8*)(&Ps[w][lr][k2 * 32 + lq * 8]);
        #pragma unroll
        for (int k2 = 0; k2 < 2; ++k2)
            #pragma unroll
            for (int nt = 0; nt < 8; ++nt) {
                short8 vf = *(const short8*)(VsT + (nt * 16 + lr) * 64 + k2 * 32 + lq * 8);
                oacc[nt] = __builtin_amdgcn_mfma_f32_16x16x32_bf16(pf[k2], vf, oacc[nt], 0, 0, 0);
            }
    }

    // epilogue: O /= l, write f32 [s][h*128+d]
    #pragma unroll
    for (int nt = 0; nt < 8; ++nt) {
        const int col = h * 128 + nt * 16 + lr;
        #pragma unroll
        for (int r = 0; r < 4; ++r) {
            const int s = q0 + w * 16 + lq * 4 + r;
            attnb[(size_t)s * 3072 + col] = oacc[nt][r] / lrow[r];
        }
    }
}

// ---------------------------------------------------------------------------
extern "C" void kernel_launch(void* const* d_in, const int* in_sizes, int n_in,
                              void* d_out, int out_size, void* d_ws, size_t ws_size,
                              hipStream_t stream)
{
    (void)in_sizes; (void)n_in; (void)out_size; (void)ws_size;
    const float* hs        = (const float*)d_in[0];
    const float* ehs       = (const float*)d_in[1];
    const float* rc        = (const float*)d_in[2];
    const float* rs        = (const float*)d_in[3];
    const float* qkv_w     = (const float*)d_in[4];
    const float* qkv_down  = (const float*)d_in[5];
    const float* qkv_up    = (const float*)d_in[6];
    const float* aqkv_w    = (const float*)d_in[7];
    const float* aqkv_down = (const float*)d_in[8];
    const float* aqkv_up   = (const float*)d_in[9];
    const float* out_w     = (const float*)d_in[10];
    const float* out_down  = (const float*)d_in[11];
    const float* out_up    = (const float*)d_in[12];
    const float* out_b     = (const float*)d_in[13];
    const float* aout_w    = (const float*)d_in[14];
    const float* aout_down = (const float*)d_in[15];
    const float* aout_up   = (const float*)d_in[16];
    const float* aout_b    = (const float*)d_in[17];
    const float* nqw  = (const float*)d_in[18];
    const float* nkw  = (const float*)d_in[19];
    const float* naqw = (const float*)d_in[20];
    const float* nakw = (const float*)d_in[21];

    char* ws = (char*)d_ws;
    size_t o = 0;
    bf16* Qb = (bf16*)(ws + o); o += (size_t)24 * 2048 * 128 * 2;
    bf16* Kb = (bf16*)(ws + o); o += (size_t)24 * 2048 * 128 * 2;
    bf16* Vb = (bf16*)(ws + o); o += (size_t)24 * 2048 * 128 * 2;  // [h][d][s]
    float* attnb = (float*)(ws + o); o += (size_t)2048 * 3072 * 4;
    float* t_img  = (float*)(ws + o); o += (size_t)1536 * 32 * 4;
    float* t_txt  = (float*)(ws + o); o += (size_t)512 * 32 * 4;
    float* t2_img = (float*)(ws + o); o += (size_t)1536 * 32 * 4;
    float* t2_txt = (float*)(ws + o); o += (size_t)512 * 32 * 4;
    float* upT_qkv  = (float*)(ws + o); o += (size_t)9216 * 32 * 4;
    float* upT_aqkv = (float*)(ws + o); o += (size_t)9216 * 32 * 4;
    float* upT_out  = (float*)(ws + o); o += (size_t)3072 * 32 * 4;
    float* upT_aout = (float*)(ws + o); o += (size_t)3072 * 32 * 4;

    transposeR<<<144, 64, 0, stream>>>(qkv_up, upT_qkv, 9216);
    transposeR<<<144, 64, 0, stream>>>(aqkv_up, upT_aqkv, 9216);
    transposeR<<<48, 64, 0, stream>>>(out_up, upT_out, 3072);
    transposeR<<<48, 64, 0, stream>>>(aout_up, upT_aout, 3072);
    downproj<<<1536, 256, 0, stream>>>(hs, qkv_down, t_img, 3072);
    downproj<<<512, 256, 0, stream>>>(ehs, aqkv_down, t_txt, 3072);

    gemm128<<<dim3(72, 12), 256, 0, stream>>>(hs, qkv_w, t_img, upT_qkv,
        nullptr, nullptr, Qb, Kb, Vb, 1536, 9216, 3072, 512, 1);
    gemm128<<<dim3(72, 4), 256, 0, stream>>>(ehs, aqkv_w, t_txt, upT_aqkv,
        nullptr, nullptr, Qb, Kb, Vb, 512, 9216, 3072, 0, 1);

    rmsrope<<<24 * 2048, 64, 0, stream>>>(Qb, Kb, rc, rs, nqw, nkw, naqw, nakw);

    attn64<<<dim3(32, 24), 256, 0, stream>>>(Qb, Kb, Vb, attnb);

    downproj<<<1536, 256, 0, stream>>>(attnb + (size_t)512 * 3072, out_down, t2_img, 3072);
    downproj<<<512, 256, 0, stream>>>(attnb, aout_down, t2_txt, 3072);

    float* outp = (float*)d_out;
    gemm128<<<dim3(24, 12), 256, 0, stream>>>(attnb + (size_t)512 * 3072, out_w,
        t2_img, upT_out, out_b, outp, nullptr, nullptr, nullptr,
        1536, 3072, 3072, 0, 0);
    gemm128<<<dim3(24, 4), 256, 0, stream>>>(attnb, aout_w,
        t2_txt, upT_aout, aout_b, outp + (size_t)1536 * 3072, nullptr, nullptr, nullptr,
        512, 3072, 3072, 0, 0);
}